// Round 9
// baseline (550.469 us; speedup 1.0000x reference)
//
#include <hip/hip_runtime.h>
#include <hip/hip_bf16.h>

// ---------- types ----------
typedef short bf16x8 __attribute__((ext_vector_type(8)));   // 8 bf16 (4 VGPRs)
typedef float f32x4  __attribute__((ext_vector_type(4)));

typedef __attribute__((address_space(1))) const unsigned int gu32_t;
typedef __attribute__((address_space(3))) unsigned int lu32_t;

__device__ inline void gld16(const void* g, void* l) {
  // async global->LDS, 16B per lane; dest must be wave-uniform-base + lane*16
  __builtin_amdgcn_global_load_lds((gu32_t*)g, (lu32_t*)l, 16, 0, 0);
}

#define S_LEN 2048
#define HID   4096
#define NH    32
#define HD    128
#define QKV_N 12288

// ---------- fp32 -> bf16 convert (vectorized, grid-stride) ----------
__global__ void cvt_bf16_kernel(const float* __restrict__ in,
                                __hip_bfloat16* __restrict__ out, long n) {
  long stride = (long)gridDim.x * blockDim.x;
  for (long i = (long)blockIdx.x * blockDim.x + threadIdx.x; i * 8 < n; i += stride) {
    long b = i * 8;
    float4 a0 = *(const float4*)(in + b);
    float4 a1 = *(const float4*)(in + b + 4);
    union { __hip_bfloat16 h[8]; bf16x8 v; } u;
    u.h[0] = __float2bfloat16(a0.x); u.h[1] = __float2bfloat16(a0.y);
    u.h[2] = __float2bfloat16(a0.z); u.h[3] = __float2bfloat16(a0.w);
    u.h[4] = __float2bfloat16(a1.x); u.h[5] = __float2bfloat16(a1.y);
    u.h[6] = __float2bfloat16(a1.z); u.h[7] = __float2bfloat16(a1.w);
    *(bf16x8*)(out + b) = u.v;
  }
}

// ================= 256x256 8-phase GEMM (QKV): C = A B^T + bias =================
// 512 threads = 8 waves (2M x 4N); per-wave 128x64 output = acc[8][4] f32x4.
// LDS: double-buffered 256x64 A + B tiles = 128 KiB. BK=64, 2 K-tiles/iter.
//
// RACE FIX (round 8): staged "halves" are the QUADRANT READ-FOOTPRINTS, not
// contiguous row blocks. Phase (mh,nh) reads A rows {wr*128+mh*64+0..63} and
// B rows {wc*64+nh*32+0..31} -> A_half(h) = rows {h*64..+63} u {128+h*64..+63};
// B_half(h) = rows {g*64+h*32..+31, g=0..3}. With these regions, every stage
// at phase p targets rows whose last read was at phase <= p-1 (barrier-
// separated), and the p4/p8 vmcnt(4) drains each stage >=2 phases before its
// first reader. (Previous round staged contiguous rows 0..127 while mh=1
// phases were still reading rows 64..127 -> in-flight DMA landed on live data.)
//
//  p1: buf1.A_h1<-T1  p2: buf1.B_h1<-T1  p3: buf0.A_h0<-T2  p4: buf0.B_h0<-T2*
//  p5: buf0.A_h1<-T2  p6: buf0.B_h1<-T2  p7: buf1.A_h0<-T3  p8: buf1.B_h0<-T3*
//  (* = s_waitcnt vmcnt(4): all but the last 2 stages landed; never 0 in-loop)
// Swizzle: 8 slots/row, slot ^= row&7 on SOURCE addr + ds_read addr (rule #21).

#define G256_STAGE_A(sbuf, h, kt) do { int kk_ = (kt) * 64;                         \
    _Pragma("unroll") for (int j_ = 0; j_ < 2; ++j_) {                              \
      int row_ = j_ * 128 + (h) * 64 + (t >> 3);  /* t>>3 in 0..63 */               \
      int sl_ = t & 7;                                                              \
      gld16(Ag + (long)(m0 + row_) * 4096 + kk_ + (sl_ ^ (row_ & 7)) * 8,           \
            &lA[sbuf][row_ * 64 + sl_ * 8]); } } while (0)

#define G256_STAGE_B(sbuf, h, kt) do { int kk_ = (kt) * 64;                         \
    _Pragma("unroll") for (int j_ = 0; j_ < 2; ++j_) {                              \
      int g_ = t >> 8;                     /* 0..1 */                               \
      int r32_ = (t >> 3) & 31;                                                     \
      int row_ = (j_ * 2 + g_) * 64 + (h) * 32 + r32_;                              \
      int sl_ = t & 7;                                                              \
      gld16(Bg + (long)(n0 + row_) * 4096 + kk_ + (sl_ ^ (row_ & 7)) * 8,           \
            &lB[sbuf][row_ * 64 + sl_ * 8]); } } while (0)

#define G256_PHASE(buf, mh, nh, STAGE_STMT, VM) do {                                \
    bf16x8 pa_[4][2], pb_[2][2];                                                    \
    _Pragma("unroll") for (int mi_ = 0; mi_ < 4; ++mi_)                             \
      _Pragma("unroll") for (int ks_ = 0; ks_ < 2; ++ks_) {                         \
        int row_ = wr * 128 + (mh) * 64 + mi_ * 16 + lr;                            \
        pa_[mi_][ks_] = *(const bf16x8*)&lA[buf][row_ * 64 +                        \
                         ((ks_ * 4 + lg) ^ (row_ & 7)) * 8]; }                      \
    _Pragma("unroll") for (int ni_ = 0; ni_ < 2; ++ni_)                             \
      _Pragma("unroll") for (int ks_ = 0; ks_ < 2; ++ks_) {                         \
        int row_ = wc * 64 + (nh) * 32 + ni_ * 16 + lr;                             \
        pb_[ni_][ks_] = *(const bf16x8*)&lB[buf][row_ * 64 +                        \
                         ((ks_ * 4 + lg) ^ (row_ & 7)) * 8]; }                      \
    STAGE_STMT;                                                                     \
    __builtin_amdgcn_s_barrier();                                                   \
    __builtin_amdgcn_s_setprio(1);                                                  \
    _Pragma("unroll") for (int mi_ = 0; mi_ < 4; ++mi_)                             \
      _Pragma("unroll") for (int ni_ = 0; ni_ < 2; ++ni_)                           \
        _Pragma("unroll") for (int ks_ = 0; ks_ < 2; ++ks_)                         \
          acc[(mh) * 4 + mi_][(nh) * 2 + ni_] =                                     \
            __builtin_amdgcn_mfma_f32_16x16x32_bf16(pa_[mi_][ks_], pb_[ni_][ks_],   \
                acc[(mh) * 4 + mi_][(nh) * 2 + ni_], 0, 0, 0);                      \
    __builtin_amdgcn_s_setprio(0);                                                  \
    if (VM) { asm volatile("s_waitcnt vmcnt(4)" ::: "memory"); }                    \
    __builtin_amdgcn_s_barrier();                                                   \
    __builtin_amdgcn_sched_barrier(0);                                              \
  } while (0)

__global__ __launch_bounds__(512, 2) void gemm256_qkv_kernel(
    const __hip_bfloat16* __restrict__ Ag,
    const __hip_bfloat16* __restrict__ Bg,
    const float* __restrict__ bias,
    __hip_bfloat16* __restrict__ Cout)
{
  __shared__ __hip_bfloat16 lA[2][256 * 64];   // 64 KiB
  __shared__ __hip_bfloat16 lB[2][256 * 64];   // 64 KiB
  const int t = threadIdx.x;
  const int w = t >> 6, l = t & 63;
  const int wr = w >> 2, wc = w & 3;
  const int lr = l & 15, lg = l >> 4;
  const int m0 = blockIdx.x * 256, n0 = blockIdx.y * 256;

  f32x4 acc[8][4] = {};

  // prologue: all 4 buf0 footprint-halves (T0) + buf1 h0 halves (T1). 12 loads.
  G256_STAGE_A(0, 0, 0); G256_STAGE_B(0, 0, 0);
  G256_STAGE_A(0, 1, 0); G256_STAGE_B(0, 1, 0);
  G256_STAGE_A(1, 0, 1); G256_STAGE_B(1, 0, 1);
  asm volatile("s_waitcnt vmcnt(4)" ::: "memory");   // buf0 fully landed
  __builtin_amdgcn_s_barrier();
  __builtin_amdgcn_sched_barrier(0);

  for (int i = 0; i < 32; ++i) {                     // tiles T0=2i (buf0), T1=2i+1 (buf1)
    const int T1 = 2 * i + 1;
    const int T2 = (2 * i + 2) & 63;                 // wrap on last iter: harmless re-stage
    const int T3 = (2 * i + 3) & 63;
    G256_PHASE(0, 0, 0, G256_STAGE_A(1, 1, T1), 0);
    G256_PHASE(0, 0, 1, G256_STAGE_B(1, 1, T1), 0);
    G256_PHASE(0, 1, 0, G256_STAGE_A(0, 0, T2), 0);
    G256_PHASE(0, 1, 1, G256_STAGE_B(0, 0, T2), 1);
    G256_PHASE(1, 0, 0, G256_STAGE_A(0, 1, T2), 0);
    G256_PHASE(1, 0, 1, G256_STAGE_B(0, 1, T2), 0);
    G256_PHASE(1, 1, 0, G256_STAGE_A(1, 0, T3), 0);
    G256_PHASE(1, 1, 1, G256_STAGE_B(1, 0, T3), 1);
  }

  // drain wrap-around stages so LDS writes can't land after block teardown
  asm volatile("s_waitcnt vmcnt(0)" ::: "memory");
  __builtin_amdgcn_s_barrier();

  #pragma unroll
  for (int mi = 0; mi < 8; ++mi) {
    #pragma unroll
    for (int ni = 0; ni < 4; ++ni) {
      int col = n0 + wc * 64 + ni * 16 + lr;
      float bv = bias[col];
      #pragma unroll
      for (int r = 0; r < 4; ++r) {
        int row = m0 + wr * 128 + mi * 16 + lg * 4 + r;  // C/D: col=lane&15, row=lg*4+reg
        Cout[(long)row * QKV_N + col] = __float2bfloat16(acc[mi][ni][r] + bv);
      }
    }
  }
}

// ---------- GEMM (m97 structure): C[m,n] = sum_k A[m,k]*B[n,k] + bias[n] ----------
// Used for the out-projection (128-tile grid 16x32 = 512 blocks, balanced).
template<int WRITE_BF16>
__global__ __launch_bounds__(256) void gemm_bt_kernel(
    const __hip_bfloat16* __restrict__ A,
    const __hip_bfloat16* __restrict__ B,
    const float* __restrict__ bias,
    void* __restrict__ Cout, int M, int N, int K)
{
  __shared__ __hip_bfloat16 lA[128 * 64];
  __shared__ __hip_bfloat16 lB[128 * 64];
  const int t = threadIdx.x;
  const int w = t >> 6, l = t & 63;
  const int lr = l & 15, lg = l >> 4;
  const int m0 = blockIdx.x * 128, n0 = blockIdx.y * 128;
  const int wm = (w >> 1) * 64, wn = (w & 1) * 64;

  f32x4 acc[4][4] = {};

  for (int k0 = 0; k0 < K; k0 += 64) {
    #pragma unroll
    for (int i = 0; i < 4; ++i) {
      int c = i * 256 + t;            // chunk id 0..1023, 16B each, linear in LDS
      int row = c >> 3, s = c & 7;    // source slot pre-swizzled: s ^ (row&7)
      gld16(A + (long)(m0 + row) * K + k0 + (s ^ (row & 7)) * 8, &lA[c * 8]);
    }
    #pragma unroll
    for (int i = 0; i < 4; ++i) {
      int c = i * 256 + t;
      int row = c >> 3, s = c & 7;
      gld16(B + (long)(n0 + row) * K + k0 + (s ^ (row & 7)) * 8, &lB[c * 8]);
    }
    __syncthreads();                  // drains vmcnt before barrier
    #pragma unroll
    for (int ks = 0; ks < 2; ++ks) {
      bf16x8 af[4], bfr[4];
      #pragma unroll
      for (int mi = 0; mi < 4; ++mi) {
        int row = wm + mi * 16 + lr;
        af[mi] = *(const bf16x8*)&lA[row * 64 + ((ks * 4 + lg) ^ (row & 7)) * 8];
      }
      #pragma unroll
      for (int ni = 0; ni < 4; ++ni) {
        int row = wn + ni * 16 + lr;
        bfr[ni] = *(const bf16x8*)&lB[row * 64 + ((ks * 4 + lg) ^ (row & 7)) * 8];
      }
      #pragma unroll
      for (int mi = 0; mi < 4; ++mi)
        #pragma unroll
        for (int ni = 0; ni < 4; ++ni)
          acc[mi][ni] = __builtin_amdgcn_mfma_f32_16x16x32_bf16(af[mi], bfr[ni], acc[mi][ni], 0, 0, 0);
    }
    __syncthreads();
  }

  #pragma unroll
  for (int mi = 0; mi < 4; ++mi) {
    #pragma unroll
    for (int ni = 0; ni < 4; ++ni) {
      int col = n0 + wn + ni * 16 + lr;
      float bv = bias[col];
      #pragma unroll
      for (int r = 0; r < 4; ++r) {
        int row = m0 + wm + mi * 16 + lg * 4 + r;     // C/D: col=lane&15, row=(lane>>4)*4+reg
        float v = acc[mi][ni][r] + bv;
        if (WRITE_BF16)
          ((__hip_bfloat16*)Cout)[(long)row * N + col] = __float2bfloat16(v);
        else
          ((float*)Cout)[(long)row * N + col] = v;
      }
    }
  }
}

// ---------- RoPE cos/sin table: [s][64] ----------
__global__ void rope_table_kernel(const int* __restrict__ pos,
                                  float* __restrict__ ct, float* __restrict__ st) {
  int s = blockIdx.x, j = threadIdx.x;      // 2048 x 64
  float p = (float)pos[s];
  // theta^(-2j/128) = 2^(-log2(10000)/64 * j)
  float invf = exp2f(-0.20762050593046013f * (float)j);
  float a = p * invf;
  ct[s * 64 + j] = cosf(a);
  st[s * 64 + j] = sinf(a);
}

// ---------- RoPE + rearrange: qkv[s][h*384+{q,k,v}*128+d] -> Qr/Kr [h][s][d], Vt [h][d][s] ----------
__global__ __launch_bounds__(256) void rope_rearrange_kernel(
    const __hip_bfloat16* __restrict__ qkv,
    const float* __restrict__ ct, const float* __restrict__ st,
    __hip_bfloat16* __restrict__ Qr, __hip_bfloat16* __restrict__ Kr,
    __hip_bfloat16* __restrict__ Vt)
{
  __shared__ __hip_bfloat16 lv[64][136];    // padded to break bank conflicts on transpose read
  const int h = blockIdx.y, s0 = blockIdx.x * 64, t = threadIdx.x;
  #pragma unroll
  for (int i = 0; i < 16; ++i) {
    int idx = i * 256 + t;                  // 64 s-rows x 64 pairs
    int si = idx >> 6, j = idx & 63;
    long base = (long)(s0 + si) * QKV_N + h * 384;
    float c  = ct[(s0 + si) * 64 + j];
    float sn = st[(s0 + si) * 64 + j];
    float q1 = __bfloat162float(qkv[base + j]);
    float q2 = __bfloat162float(qkv[base + 64 + j]);
    float k1 = __bfloat162float(qkv[base + 128 + j]);
    float k2 = __bfloat162float(qkv[base + 192 + j]);
    long ob = (long)h * (S_LEN * HD) + (long)(s0 + si) * HD;
    Qr[ob + j]      = __float2bfloat16(q1 * c - q2 * sn);
    Qr[ob + 64 + j] = __float2bfloat16(q2 * c + q1 * sn);
    Kr[ob + j]      = __float2bfloat16(k1 * c - k2 * sn);
    Kr[ob + 64 + j] = __float2bfloat16(k2 * c + k1 * sn);
    lv[si][j]      = qkv[base + 256 + j];
    lv[si][64 + j] = qkv[base + 320 + j];
  }
  __syncthreads();
  #pragma unroll
  for (int i = 0; i < 4; ++i) {
    int c = i * 256 + t;                    // 128 d x 8 chunks of 8 s
    int d = c >> 3, s8 = (c & 7) * 8;
    union { __hip_bfloat16 h8[8]; bf16x8 v; } u;
    #pragma unroll
    for (int j2 = 0; j2 < 8; ++j2) u.h8[j2] = lv[s8 + j2][d];
    *(bf16x8*)(Vt + (long)h * (HD * S_LEN) + (long)d * S_LEN + s0 + s8) = u.v;
  }
}

// ---------- causal flash attention, paired q-tiles for uniform work ----------
// QBLK=64. q-tile qt (64 rows) needs qt+1 k-tiles (64-wide). Block p handles
// q-tiles {p, 31-p}: (p+1)+(32-p) = 33 k-tiles per block, UNIFORM across all
// 512 blocks (16 pairs x 32 heads) -> no causal tail imbalance.
// 4 waves; wave w owns q rows [qt*64 + w*16, +16).
// lK: 16 slots/row, swizzle row&15; lV: 8 slots/row, swizzle row&7.
__global__ __launch_bounds__(256) void flash_attn_kernel(
    const __hip_bfloat16* __restrict__ Qr, const __hip_bfloat16* __restrict__ Kr,
    const __hip_bfloat16* __restrict__ Vt, __hip_bfloat16* __restrict__ O)
{
  __shared__ __hip_bfloat16 lK[64 * 128];   // [k][d] 16KB
  __shared__ __hip_bfloat16 lV[128 * 64];   // [d][k] 16KB
  __shared__ __hip_bfloat16 lP[4][16 * 72]; // per-wave P (16 rows), padded stride
  const int h = blockIdx.y, pair = blockIdx.x;
  const int t = threadIdx.x, w = t >> 6, l = t & 63;
  const int lr = l & 15, lg = l >> 4;
  const __hip_bfloat16* Qh = Qr + (long)h * (S_LEN * HD);
  const __hip_bfloat16* Kh = Kr + (long)h * (S_LEN * HD);
  const __hip_bfloat16* Vh = Vt + (long)h * (HD * S_LEN);
  const float sc = 0.08838834764831845f;    // 1/sqrt(128)

  for (int ph = 0; ph < 2; ++ph) {
    const int qt = ph ? (31 - pair) : pair;
    const int q0 = qt * 64;

    // hoist this q-tile's Q fragments to registers
    bf16x8 qf[4];
    #pragma unroll
    for (int ks = 0; ks < 4; ++ks)
      qf[ks] = *(const bf16x8*)(Qh + (long)(q0 + w * 16 + lr) * HD + ks * 32 + lg * 8);

    float m_r[4], l_r[4];
    f32x4 oacc[8] = {};
    #pragma unroll
    for (int r = 0; r < 4; ++r) { m_r[r] = -1e30f; l_r[r] = 0.f; }

    const int ktiles = qt + 1;              // causal: k <= q0+63
    for (int kt = 0; kt < ktiles; ++kt) {
      const int k0 = kt * 64;
      #pragma unroll
      for (int i = 0; i < 4; ++i) {         // K tile: 64 k x 128 d
        int c = i * 256 + t;
        int row = c >> 4, s = c & 15;
        gld16(Kh + (long)(k0 + row) * HD + (s ^ (row & 15)) * 8, &lK[c * 8]);
      }
      #pragma unroll
      for (int i = 0; i < 4; ++i) {         // V^T tile: 128 d x 64 k
        int c = i * 256 + t;
        int d = c >> 3, s = c & 7;
        gld16(Vh + (long)d * S_LEN + k0 + (s ^ (d & 7)) * 8, &lV[c * 8]);
      }
      __syncthreads();

      // S = Q K^T (one 16-row m-frag per wave)
      f32x4 s[4] = {};
      #pragma unroll
      for (int ks = 0; ks < 4; ++ks) {
        bf16x8 kf[4];
        #pragma unroll
        for (int nf = 0; nf < 4; ++nf) {
          int row = nf * 16 + lr;
          kf[nf] = *(const bf16x8*)&lK[row * 128 + ((ks * 4 + lg) ^ (row & 15)) * 8];
        }
        #pragma unroll
        for (int nf = 0; nf < 4; ++nf)
          s[nf] = __builtin_amdgcn_mfma_f32_16x16x32_bf16(qf[ks], kf[nf], s[nf], 0, 0, 0);
      }

      // online softmax (wave-parallel; 16-lane group shuffles)
      #pragma unroll
      for (int r = 0; r < 4; ++r) {
        int q = q0 + w * 16 + lg * 4 + r;
        float mx = -1e30f;
        #pragma unroll
        for (int nf = 0; nf < 4; ++nf) {
          int k = k0 + nf * 16 + lr;
          float v = s[nf][r] * sc;
          if (k > q) v = -1e30f;            // causal mask (only diagonal tile masks)
          s[nf][r] = v;
          mx = fmaxf(mx, v);
        }
        #pragma unroll
        for (int mk = 1; mk < 16; mk <<= 1) mx = fmaxf(mx, __shfl_xor(mx, mk));
        float mo = m_r[r];
        float mn = fmaxf(mo, mx);
        m_r[r] = mn;
        float alpha = __expf(mo - mn);
        float rs = 0.f;
        #pragma unroll
        for (int nf = 0; nf < 4; ++nf) {
          float p = __expf(s[nf][r] - mn);
          s[nf][r] = p;
          rs += p;
        }
        #pragma unroll
        for (int mk = 1; mk < 16; mk <<= 1) rs += __shfl_xor(rs, mk);
        l_r[r] = l_r[r] * alpha + rs;
        // rescale ONLY this row's accumulator component (r-th lane of the f32x4)
        #pragma unroll
        for (int df = 0; df < 8; ++df) oacc[df][r] *= alpha;
      }

      // P -> LDS (per-wave region), then PV
      #pragma unroll
      for (int nf = 0; nf < 4; ++nf)
        #pragma unroll
        for (int r = 0; r < 4; ++r)
          lP[w][(lg * 4 + r) * 72 + nf * 16 + lr] = __float2bfloat16(s[nf][r]);
      asm volatile("s_waitcnt lgkmcnt(0)" ::: "memory");

      #pragma unroll
      for (int ks2 = 0; ks2 < 2; ++ks2) {
        bf16x8 pa = *(const bf16x8*)&lP[w][lr * 72 + ks2 * 32 + lg * 8];
        #pragma unroll
        for (int df = 0; df < 8; ++df) {
          int row = df * 16 + lr;
          bf16x8 vf = *(const bf16x8*)&lV[row * 64 + ((ks2 * 4 + lg) ^ (row & 7)) * 8];
          oacc[df] = __builtin_amdgcn_mfma_f32_16x16x32_bf16(pa, vf, oacc[df], 0, 0, 0);
        }
      }
      __syncthreads();
    }

    // normalize + write O[s][h*128+d]
    #pragma unroll
    for (int r = 0; r < 4; ++r) {
      float inv = 1.f / l_r[r];
      long q = q0 + w * 16 + lg * 4 + r;
      #pragma unroll
      for (int df = 0; df < 8; ++df)
        O[q * HID + h * HD + df * 16 + lr] = __float2bfloat16(oacc[df][r] * inv);
    }
    __syncthreads();                        // phase boundary: lK/lV reuse
  }
}

// ---------- launcher ----------
extern "C" void kernel_launch(void* const* d_in, const int* in_sizes, int n_in,
                              void* d_out, int out_size, void* d_ws, size_t ws_size,
                              hipStream_t stream)
{
  (void)in_sizes; (void)n_in; (void)out_size;
  const float* hidden = (const float*)d_in[0];
  const int*   pos    = (const int*)d_in[1];
  const float* wqkv_w = (const float*)d_in[2];
  const float* wqkv_b = (const float*)d_in[3];
  const float* wo_w   = (const float*)d_in[4];
  const float* wo_b   = (const float*)d_in[5];
  float* out = (float*)d_out;

  // ws layout (bytes). Phase 1: hid_bf | wqkv_bf | qkv_bf.
  // Phase 2+ reuses hid_bf region as Qr, wqkv_bf region as Kr/Vt/Obf/Wo_bf/tables.
  char* ws = (char*)d_ws;
  if (ws_size < 167772160UL) return;        // need 160 MB
  __hip_bfloat16* hid_bf  = (__hip_bfloat16*)(ws + 0);          // 16 MB, later Qr
  __hip_bfloat16* wqkv_bf = (__hip_bfloat16*)(ws + 16777216);   // 96 MB
  __hip_bfloat16* qr      = (__hip_bfloat16*)(ws + 0);
  __hip_bfloat16* kr      = (__hip_bfloat16*)(ws + 16777216);
  __hip_bfloat16* vt      = (__hip_bfloat16*)(ws + 33554432);
  __hip_bfloat16* obf     = (__hip_bfloat16*)(ws + 50331648);
  __hip_bfloat16* wo_bf   = (__hip_bfloat16*)(ws + 67108864);   // 32 MB
  float*          cos_t   = (float*)(ws + 100663296);
  float*          sin_t   = (float*)(ws + 100663296 + 524288);
  __hip_bfloat16* qkv_bf  = (__hip_bfloat16*)(ws + 117440512);  // 48 MB -> total 160 MB

  cvt_bf16_kernel<<<4096, 256, 0, stream>>>(hidden, hid_bf, 8388608L);
  cvt_bf16_kernel<<<8192, 256, 0, stream>>>(wqkv_w, wqkv_bf, 50331648L);
  gemm256_qkv_kernel<<<dim3(8, 48), 512, 0, stream>>>(hid_bf, wqkv_bf, wqkv_b, qkv_bf);
  // safe to overwrite wqkv region only after the QKV GEMM
  cvt_bf16_kernel<<<8192, 256, 0, stream>>>(wo_w, wo_bf, 16777216L);
  rope_table_kernel<<<2048, 64, 0, stream>>>(pos, cos_t, sin_t);
  rope_rearrange_kernel<<<dim3(32, 32), 256, 0, stream>>>(qkv_bf, cos_t, sin_t, qr, kr, vt);
  flash_attn_kernel<<<dim3(16, 32), 256, 0, stream>>>(qr, kr, vt, obf);
  gemm_bt_kernel<0><<<dim3(16, 32), 256, 0, stream>>>(obf, wo_bf, wo_b, out, 2048, 4096, 4096);
}

// Round 10
// 488.536 us; speedup vs baseline: 1.1268x; 1.1268x over previous
//
#include <hip/hip_runtime.h>
#include <hip/hip_bf16.h>

// ---------- types ----------
typedef short bf16x8 __attribute__((ext_vector_type(8)));   // 8 bf16 (4 VGPRs)
typedef float f32x4  __attribute__((ext_vector_type(4)));

typedef __attribute__((address_space(1))) const unsigned int gu32_t;
typedef __attribute__((address_space(3))) unsigned int lu32_t;

__device__ inline void gld16(const void* g, void* l) {
  // async global->LDS, 16B per lane; dest must be wave-uniform-base + lane*16
  __builtin_amdgcn_global_load_lds((gu32_t*)g, (lu32_t*)l, 16, 0, 0);
}

#define S_LEN 2048
#define HID   4096
#define NH    32
#define HD    128
#define QKV_N 12288

// ---------- fp32 -> bf16 convert (vectorized, grid-stride) ----------
__global__ void cvt_bf16_kernel(const float* __restrict__ in,
                                __hip_bfloat16* __restrict__ out, long n) {
  long stride = (long)gridDim.x * blockDim.x;
  for (long i = (long)blockIdx.x * blockDim.x + threadIdx.x; i * 8 < n; i += stride) {
    long b = i * 8;
    float4 a0 = *(const float4*)(in + b);
    float4 a1 = *(const float4*)(in + b + 4);
    union { __hip_bfloat16 h[8]; bf16x8 v; } u;
    u.h[0] = __float2bfloat16(a0.x); u.h[1] = __float2bfloat16(a0.y);
    u.h[2] = __float2bfloat16(a0.z); u.h[3] = __float2bfloat16(a0.w);
    u.h[4] = __float2bfloat16(a1.x); u.h[5] = __float2bfloat16(a1.y);
    u.h[6] = __float2bfloat16(a1.z); u.h[7] = __float2bfloat16(a1.w);
    *(bf16x8*)(out + b) = u.v;
  }
}

// ================= 256x256 8-phase GEMM (QKV): C = A B^T + bias =================
// 512 threads = 8 waves (2M x 4N); per-wave 128x64 output = acc[8][4] f32x4.
// LDS: double-buffered 256x64 A + B tiles = 128 KiB. BK=64, 2 K-tiles/iter.
//
// Stage/drain schedule (race-free, verified round 9): footprint-halves
// A_h(h) = rows {h*64..+63} u {128+h*64..+63}; B_h(h) = {g*64+h*32..+31}.
//  p1: buf1.A_h1<-T1  p2: buf1.B_h1<-T1  p3: buf0.A_h0<-T2  p4: buf0.B_h0<-T2*
//  p5: buf0.A_h1<-T2  p6: buf0.B_h1<-T2  p7: buf1.A_h0<-T3  p8: buf1.B_h0<-T3*
//  (* = s_waitcnt vmcnt(4); never 0 in-loop)
//
// ROUND 10 CHANGE (LDS-read critical path): register-reuse quadrant order.
// Round 9 re-read 12 frags/phase (96 reads/wave/iter = 768KB/CU > MFMA time).
// Now per K-tile: p1 loads A0(8)+B0(4); p2 loads B1(4), reuses A0; p3 loads
// A1(8), reuses B0; p4 loads nothing (A1,B1 from regs) -> 24 reads/K-tile,
// LDS path halved below MFMA demand. Also dropped per-phase sched_barrier(0)
// (m141 order-pinning anti-pattern); hoist-safety: every cross-phase ds_read
// is fenced by a vmcnt asm with "memory" clobber, and gld16's LDS write
// aliases the re-staged region so program order vs prior reads is preserved.
// Swizzle: 8 slots/row, slot ^= row&7 on SOURCE addr + ds_read addr.

#define G256_STAGE_A(sbuf, h, kt) do { int kk_ = (kt) * 64;                         \
    _Pragma("unroll") for (int j_ = 0; j_ < 2; ++j_) {                              \
      int row_ = j_ * 128 + (h) * 64 + (t >> 3);  /* t>>3 in 0..63 */               \
      int sl_ = t & 7;                                                              \
      gld16(Ag + (long)(m0 + row_) * 4096 + kk_ + (sl_ ^ (row_ & 7)) * 8,           \
            &lA[sbuf][row_ * 64 + sl_ * 8]); } } while (0)

#define G256_STAGE_B(sbuf, h, kt) do { int kk_ = (kt) * 64;                         \
    _Pragma("unroll") for (int j_ = 0; j_ < 2; ++j_) {                              \
      int g_ = t >> 8;                     /* 0..1 */                               \
      int r32_ = (t >> 3) & 31;                                                     \
      int row_ = (j_ * 2 + g_) * 64 + (h) * 32 + r32_;                              \
      int sl_ = t & 7;                                                              \
      gld16(Bg + (long)(n0 + row_) * 4096 + kk_ + (sl_ ^ (row_ & 7)) * 8,           \
            &lB[sbuf][row_ * 64 + sl_ * 8]); } } while (0)

#define G256_LDA(DST, buf, mh) do {                                                 \
    _Pragma("unroll") for (int mi_ = 0; mi_ < 4; ++mi_)                             \
      _Pragma("unroll") for (int ks_ = 0; ks_ < 2; ++ks_) {                         \
        int row_ = wr * 128 + (mh) * 64 + mi_ * 16 + lr;                            \
        DST[mi_][ks_] = *(const bf16x8*)&lA[buf][row_ * 64 +                        \
                         ((ks_ * 4 + lg) ^ (row_ & 7)) * 8]; } } while (0)

#define G256_LDB(DST, buf, nh) do {                                                 \
    _Pragma("unroll") for (int ni_ = 0; ni_ < 2; ++ni_)                             \
      _Pragma("unroll") for (int ks_ = 0; ks_ < 2; ++ks_) {                         \
        int row_ = wc * 64 + (nh) * 32 + ni_ * 16 + lr;                             \
        DST[ni_][ks_] = *(const bf16x8*)&lB[buf][row_ * 64 +                        \
                         ((ks_ * 4 + lg) ^ (row_ & 7)) * 8]; } } while (0)

#define G256_MFMA(mh, nh, PA, PB) do {                                              \
    __builtin_amdgcn_s_setprio(1);                                                  \
    _Pragma("unroll") for (int mi_ = 0; mi_ < 4; ++mi_)                             \
      _Pragma("unroll") for (int ni_ = 0; ni_ < 2; ++ni_)                           \
        _Pragma("unroll") for (int ks_ = 0; ks_ < 2; ++ks_)                         \
          acc[(mh) * 4 + mi_][(nh) * 2 + ni_] =                                     \
            __builtin_amdgcn_mfma_f32_16x16x32_bf16(PA[mi_][ks_], PB[ni_][ks_],     \
                acc[(mh) * 4 + mi_][(nh) * 2 + ni_], 0, 0, 0);                      \
    __builtin_amdgcn_s_setprio(0);                                                  \
  } while (0)

__global__ __launch_bounds__(512, 2) void gemm256_qkv_kernel(
    const __hip_bfloat16* __restrict__ Ag,
    const __hip_bfloat16* __restrict__ Bg,
    const float* __restrict__ bias,
    __hip_bfloat16* __restrict__ Cout)
{
  __shared__ __hip_bfloat16 lA[2][256 * 64];   // 64 KiB
  __shared__ __hip_bfloat16 lB[2][256 * 64];   // 64 KiB
  const int t = threadIdx.x;
  const int w = t >> 6, l = t & 63;
  const int wr = w >> 2, wc = w & 3;
  const int lr = l & 15, lg = l >> 4;
  const int m0 = blockIdx.x * 256, n0 = blockIdx.y * 256;

  f32x4 acc[8][4] = {};

  // prologue: all 4 buf0 footprint-halves (T0) + buf1 h0 halves (T1). 12 loads.
  G256_STAGE_A(0, 0, 0); G256_STAGE_B(0, 0, 0);
  G256_STAGE_A(0, 1, 0); G256_STAGE_B(0, 1, 0);
  G256_STAGE_A(1, 0, 1); G256_STAGE_B(1, 0, 1);
  asm volatile("s_waitcnt vmcnt(4)" ::: "memory");   // buf0 fully landed
  __builtin_amdgcn_s_barrier();

  for (int i = 0; i < 32; ++i) {                     // tiles T0=2i (buf0), T1=2i+1 (buf1)
    const int T1 = 2 * i + 1;
    const int T2 = (2 * i + 2) & 63;                 // wrap on last iter: harmless re-stage
    const int T3 = (2 * i + 3) & 63;
    bf16x8 pa0[4][2], pa1[4][2], pb0[2][2], pb1[2][2];

    // ---- buf0 (K-tile T0) ----
    G256_LDA(pa0, 0, 0); G256_LDB(pb0, 0, 0);        // p1: 12 reads
    G256_STAGE_A(1, 1, T1);
    __builtin_amdgcn_s_barrier();
    G256_MFMA(0, 0, pa0, pb0);
    __builtin_amdgcn_s_barrier();

    G256_LDB(pb1, 0, 1);                             // p2: 4 reads (A0 reused)
    G256_STAGE_B(1, 1, T1);
    __builtin_amdgcn_s_barrier();
    G256_MFMA(0, 1, pa0, pb1);
    __builtin_amdgcn_s_barrier();

    G256_LDA(pa1, 0, 1);                             // p3: 8 reads (B0 reused)
    G256_STAGE_A(0, 0, T2);
    __builtin_amdgcn_s_barrier();
    G256_MFMA(1, 0, pa1, pb0);
    __builtin_amdgcn_s_barrier();

    G256_STAGE_B(0, 0, T2);                          // p4: 0 reads (A1,B1 reused)
    __builtin_amdgcn_s_barrier();
    G256_MFMA(1, 1, pa1, pb1);
    asm volatile("s_waitcnt vmcnt(4)" ::: "memory");
    __builtin_amdgcn_s_barrier();

    // ---- buf1 (K-tile T1) ----
    G256_LDA(pa0, 1, 0); G256_LDB(pb0, 1, 0);        // p5
    G256_STAGE_A(0, 1, T2);
    __builtin_amdgcn_s_barrier();
    G256_MFMA(0, 0, pa0, pb0);
    __builtin_amdgcn_s_barrier();

    G256_LDB(pb1, 1, 1);                             // p6
    G256_STAGE_B(0, 1, T2);
    __builtin_amdgcn_s_barrier();
    G256_MFMA(0, 1, pa0, pb1);
    __builtin_amdgcn_s_barrier();

    G256_LDA(pa1, 1, 1);                             // p7
    G256_STAGE_A(1, 0, T3);
    __builtin_amdgcn_s_barrier();
    G256_MFMA(1, 0, pa1, pb0);
    __builtin_amdgcn_s_barrier();

    G256_STAGE_B(1, 0, T3);                          // p8
    __builtin_amdgcn_s_barrier();
    G256_MFMA(1, 1, pa1, pb1);
    asm volatile("s_waitcnt vmcnt(4)" ::: "memory");
    __builtin_amdgcn_s_barrier();
  }

  // drain wrap-around stages so LDS writes can't land after block teardown
  asm volatile("s_waitcnt vmcnt(0)" ::: "memory");
  __builtin_amdgcn_s_barrier();

  #pragma unroll
  for (int mi = 0; mi < 8; ++mi) {
    #pragma unroll
    for (int ni = 0; ni < 4; ++ni) {
      int col = n0 + wc * 64 + ni * 16 + lr;
      float bv = bias[col];
      #pragma unroll
      for (int r = 0; r < 4; ++r) {
        int row = m0 + wr * 128 + mi * 16 + lg * 4 + r;  // C/D: col=lane&15, row=lg*4+reg
        Cout[(long)row * QKV_N + col] = __float2bfloat16(acc[mi][ni][r] + bv);
      }
    }
  }
}

// ---------- GEMM (m97 structure): C[m,n] = sum_k A[m,k]*B[n,k] + bias[n] ----------
// Used for the out-projection (128-tile grid 16x32 = 512 blocks, balanced).
template<int WRITE_BF16>
__global__ __launch_bounds__(256) void gemm_bt_kernel(
    const __hip_bfloat16* __restrict__ A,
    const __hip_bfloat16* __restrict__ B,
    const float* __restrict__ bias,
    void* __restrict__ Cout, int M, int N, int K)
{
  __shared__ __hip_bfloat16 lA[128 * 64];
  __shared__ __hip_bfloat16 lB[128 * 64];
  const int t = threadIdx.x;
  const int w = t >> 6, l = t & 63;
  const int lr = l & 15, lg = l >> 4;
  const int m0 = blockIdx.x * 128, n0 = blockIdx.y * 128;
  const int wm = (w >> 1) * 64, wn = (w & 1) * 64;

  f32x4 acc[4][4] = {};

  for (int k0 = 0; k0 < K; k0 += 64) {
    #pragma unroll
    for (int i = 0; i < 4; ++i) {
      int c = i * 256 + t;            // chunk id 0..1023, 16B each, linear in LDS
      int row = c >> 3, s = c & 7;    // source slot pre-swizzled: s ^ (row&7)
      gld16(A + (long)(m0 + row) * K + k0 + (s ^ (row & 7)) * 8, &lA[c * 8]);
    }
    #pragma unroll
    for (int i = 0; i < 4; ++i) {
      int c = i * 256 + t;
      int row = c >> 3, s = c & 7;
      gld16(B + (long)(n0 + row) * K + k0 + (s ^ (row & 7)) * 8, &lB[c * 8]);
    }
    __syncthreads();                  // drains vmcnt before barrier
    #pragma unroll
    for (int ks = 0; ks < 2; ++ks) {
      bf16x8 af[4], bfr[4];
      #pragma unroll
      for (int mi = 0; mi < 4; ++mi) {
        int row = wm + mi * 16 + lr;
        af[mi] = *(const bf16x8*)&lA[row * 64 + ((ks * 4 + lg) ^ (row & 7)) * 8];
      }
      #pragma unroll
      for (int ni = 0; ni < 4; ++ni) {
        int row = wn + ni * 16 + lr;
        bfr[ni] = *(const bf16x8*)&lB[row * 64 + ((ks * 4 + lg) ^ (row & 7)) * 8];
      }
      #pragma unroll
      for (int mi = 0; mi < 4; ++mi)
        #pragma unroll
        for (int ni = 0; ni < 4; ++ni)
          acc[mi][ni] = __builtin_amdgcn_mfma_f32_16x16x32_bf16(af[mi], bfr[ni], acc[mi][ni], 0, 0, 0);
    }
    __syncthreads();
  }

  #pragma unroll
  for (int mi = 0; mi < 4; ++mi) {
    #pragma unroll
    for (int ni = 0; ni < 4; ++ni) {
      int col = n0 + wn + ni * 16 + lr;
      float bv = bias[col];
      #pragma unroll
      for (int r = 0; r < 4; ++r) {
        int row = m0 + wm + mi * 16 + lg * 4 + r;     // C/D: col=lane&15, row=(lane>>4)*4+reg
        float v = acc[mi][ni][r] + bv;
        if (WRITE_BF16)
          ((__hip_bfloat16*)Cout)[(long)row * N + col] = __float2bfloat16(v);
        else
          ((float*)Cout)[(long)row * N + col] = v;
      }
    }
  }
}

// ---------- RoPE cos/sin table: [s][64] ----------
__global__ void rope_table_kernel(const int* __restrict__ pos,
                                  float* __restrict__ ct, float* __restrict__ st) {
  int s = blockIdx.x, j = threadIdx.x;      // 2048 x 64
  float p = (float)pos[s];
  // theta^(-2j/128) = 2^(-log2(10000)/64 * j)
  float invf = exp2f(-0.20762050593046013f * (float)j);
  float a = p * invf;
  ct[s * 64 + j] = cosf(a);
  st[s * 64 + j] = sinf(a);
}

// ---------- RoPE + rearrange: qkv[s][h*384+{q,k,v}*128+d] -> Qr/Kr [h][s][d], Vt [h][d][s] ----------
__global__ __launch_bounds__(256) void rope_rearrange_kernel(
    const __hip_bfloat16* __restrict__ qkv,
    const float* __restrict__ ct, const float* __restrict__ st,
    __hip_bfloat16* __restrict__ Qr, __hip_bfloat16* __restrict__ Kr,
    __hip_bfloat16* __restrict__ Vt)
{
  __shared__ __hip_bfloat16 lv[64][136];    // padded to break bank conflicts on transpose read
  const int h = blockIdx.y, s0 = blockIdx.x * 64, t = threadIdx.x;
  #pragma unroll
  for (int i = 0; i < 16; ++i) {
    int idx = i * 256 + t;                  // 64 s-rows x 64 pairs
    int si = idx >> 6, j = idx & 63;
    long base = (long)(s0 + si) * QKV_N + h * 384;
    float c  = ct[(s0 + si) * 64 + j];
    float sn = st[(s0 + si) * 64 + j];
    float q1 = __bfloat162float(qkv[base + j]);
    float q2 = __bfloat162float(qkv[base + 64 + j]);
    float k1 = __bfloat162float(qkv[base + 128 + j]);
    float k2 = __bfloat162float(qkv[base + 192 + j]);
    long ob = (long)h * (S_LEN * HD) + (long)(s0 + si) * HD;
    Qr[ob + j]      = __float2bfloat16(q1 * c - q2 * sn);
    Qr[ob + 64 + j] = __float2bfloat16(q2 * c + q1 * sn);
    Kr[ob + j]      = __float2bfloat16(k1 * c - k2 * sn);
    Kr[ob + 64 + j] = __float2bfloat16(k2 * c + k1 * sn);
    lv[si][j]      = qkv[base + 256 + j];
    lv[si][64 + j] = qkv[base + 320 + j];
  }
  __syncthreads();
  #pragma unroll
  for (int i = 0; i < 4; ++i) {
    int c = i * 256 + t;                    // 128 d x 8 chunks of 8 s
    int d = c >> 3, s8 = (c & 7) * 8;
    union { __hip_bfloat16 h8[8]; bf16x8 v; } u;
    #pragma unroll
    for (int j2 = 0; j2 < 8; ++j2) u.h8[j2] = lv[s8 + j2][d];
    *(bf16x8*)(Vt + (long)h * (HD * S_LEN) + (long)d * S_LEN + s0 + s8) = u.v;
  }
}

// ---------- causal flash attention, paired q-tiles for uniform work ----------
// QBLK=64. q-tile qt (64 rows) needs qt+1 k-tiles (64-wide). Block p handles
// q-tiles {p, 31-p}: (p+1)+(32-p) = 33 k-tiles per block, UNIFORM across all
// 512 blocks (16 pairs x 32 heads) -> no causal tail imbalance.
// 4 waves; wave w owns q rows [qt*64 + w*16, +16).
// lK: 16 slots/row, swizzle row&15; lV: 8 slots/row, swizzle row&7.
__global__ __launch_bounds__(256) void flash_attn_kernel(
    const __hip_bfloat16* __restrict__ Qr, const __hip_bfloat16* __restrict__ Kr,
    const __hip_bfloat16* __restrict__ Vt, __hip_bfloat16* __restrict__ O)
{
  __shared__ __hip_bfloat16 lK[64 * 128];   // [k][d] 16KB
  __shared__ __hip_bfloat16 lV[128 * 64];   // [d][k] 16KB
  __shared__ __hip_bfloat16 lP[4][16 * 72]; // per-wave P (16 rows), padded stride
  const int h = blockIdx.y, pair = blockIdx.x;
  const int t = threadIdx.x, w = t >> 6, l = t & 63;
  const int lr = l & 15, lg = l >> 4;
  const __hip_bfloat16* Qh = Qr + (long)h * (S_LEN * HD);
  const __hip_bfloat16* Kh = Kr + (long)h * (S_LEN * HD);
  const __hip_bfloat16* Vh = Vt + (long)h * (HD * S_LEN);
  const float sc = 0.08838834764831845f;    // 1/sqrt(128)

  for (int ph = 0; ph < 2; ++ph) {
    const int qt = ph ? (31 - pair) : pair;
    const int q0 = qt * 64;

    // hoist this q-tile's Q fragments to registers
    bf16x8 qf[4];
    #pragma unroll
    for (int ks = 0; ks < 4; ++ks)
      qf[ks] = *(const bf16x8*)(Qh + (long)(q0 + w * 16 + lr) * HD + ks * 32 + lg * 8);

    float m_r[4], l_r[4];
    f32x4 oacc[8] = {};
    #pragma unroll
    for (int r = 0; r < 4; ++r) { m_r[r] = -1e30f; l_r[r] = 0.f; }

    const int ktiles = qt + 1;              // causal: k <= q0+63
    for (int kt = 0; kt < ktiles; ++kt) {
      const int k0 = kt * 64;
      #pragma unroll
      for (int i = 0; i < 4; ++i) {         // K tile: 64 k x 128 d
        int c = i * 256 + t;
        int row = c >> 4, s = c & 15;
        gld16(Kh + (long)(k0 + row) * HD + (s ^ (row & 15)) * 8, &lK[c * 8]);
      }
      #pragma unroll
      for (int i = 0; i < 4; ++i) {         // V^T tile: 128 d x 64 k
        int c = i * 256 + t;
        int d = c >> 3, s = c & 7;
        gld16(Vh + (long)d * S_LEN + k0 + (s ^ (d & 7)) * 8, &lV[c * 8]);
      }
      __syncthreads();

      // S = Q K^T (one 16-row m-frag per wave)
      f32x4 s[4] = {};
      #pragma unroll
      for (int ks = 0; ks < 4; ++ks) {
        bf16x8 kf[4];
        #pragma unroll
        for (int nf = 0; nf < 4; ++nf) {
          int row = nf * 16 + lr;
          kf[nf] = *(const bf16x8*)&lK[row * 128 + ((ks * 4 + lg) ^ (row & 15)) * 8];
        }
        #pragma unroll
        for (int nf = 0; nf < 4; ++nf)
          s[nf] = __builtin_amdgcn_mfma_f32_16x16x32_bf16(qf[ks], kf[nf], s[nf], 0, 0, 0);
      }

      // online softmax (wave-parallel; 16-lane group shuffles)
      #pragma unroll
      for (int r = 0; r < 4; ++r) {
        int q = q0 + w * 16 + lg * 4 + r;
        float mx = -1e30f;
        #pragma unroll
        for (int nf = 0; nf < 4; ++nf) {
          int k = k0 + nf * 16 + lr;
          float v = s[nf][r] * sc;
          if (k > q) v = -1e30f;            // causal mask (only diagonal tile masks)
          s[nf][r] = v;
          mx = fmaxf(mx, v);
        }
        #pragma unroll
        for (int mk = 1; mk < 16; mk <<= 1) mx = fmaxf(mx, __shfl_xor(mx, mk));
        float mo = m_r[r];
        float mn = fmaxf(mo, mx);
        m_r[r] = mn;
        float alpha = __expf(mo - mn);
        float rs = 0.f;
        #pragma unroll
        for (int nf = 0; nf < 4; ++nf) {
          float p = __expf(s[nf][r] - mn);
          s[nf][r] = p;
          rs += p;
        }
        #pragma unroll
        for (int mk = 1; mk < 16; mk <<= 1) rs += __shfl_xor(rs, mk);
        l_r[r] = l_r[r] * alpha + rs;
        // rescale ONLY this row's accumulator component (r-th lane of the f32x4)
        #pragma unroll
        for (int df = 0; df < 8; ++df) oacc[df][r] *= alpha;
      }

      // P -> LDS (per-wave region), then PV
      #pragma unroll
      for (int nf = 0; nf < 4; ++nf)
        #pragma unroll
        for (int r = 0; r < 4; ++r)
          lP[w][(lg * 4 + r) * 72 + nf * 16 + lr] = __float2bfloat16(s[nf][r]);
      asm volatile("s_waitcnt lgkmcnt(0)" ::: "memory");

      #pragma unroll
      for (int ks2 = 0; ks2 < 2; ++ks2) {
        bf16x8 pa = *(const bf16x8*)&lP[w][lr * 72 + ks2 * 32 + lg * 8];
        #pragma unroll
        for (int df = 0; df < 8; ++df) {
          int row = df * 16 + lr;
          bf16x8 vf = *(const bf16x8*)&lV[row * 64 + ((ks2 * 4 + lg) ^ (row & 7)) * 8];
          oacc[df] = __builtin_amdgcn_mfma_f32_16x16x32_bf16(pa, vf, oacc[df], 0, 0, 0);
        }
      }
      __syncthreads();
    }

    // normalize + write O[s][h*128+d]
    #pragma unroll
    for (int r = 0; r < 4; ++r) {
      float inv = 1.f / l_r[r];
      long q = q0 + w * 16 + lg * 4 + r;
      #pragma unroll
      for (int df = 0; df < 8; ++df)
        O[q * HID + h * HD + df * 16 + lr] = __float2bfloat16(oacc[df][r] * inv);
    }
    __syncthreads();                        // phase boundary: lK/lV reuse
  }
}

// ---------- launcher ----------
extern "C" void kernel_launch(void* const* d_in, const int* in_sizes, int n_in,
                              void* d_out, int out_size, void* d_ws, size_t ws_size,
                              hipStream_t stream)
{
  (void)in_sizes; (void)n_in; (void)out_size;
  const float* hidden = (const float*)d_in[0];
  const int*   pos    = (const int*)d_in[1];
  const float* wqkv_w = (const float*)d_in[2];
  const float* wqkv_b = (const float*)d_in[3];
  const float* wo_w   = (const float*)d_in[4];
  const float* wo_b   = (const float*)d_in[5];
  float* out = (float*)d_out;

  // ws layout (bytes). Phase 1: hid_bf | wqkv_bf | qkv_bf.
  // Phase 2+ reuses hid_bf region as Qr, wqkv_bf region as Kr/Vt/Obf/Wo_bf/tables.
  char* ws = (char*)d_ws;
  if (ws_size < 167772160UL) return;        // need 160 MB
  __hip_bfloat16* hid_bf  = (__hip_bfloat16*)(ws + 0);          // 16 MB, later Qr
  __hip_bfloat16* wqkv_bf = (__hip_bfloat16*)(ws + 16777216);   // 96 MB
  __hip_bfloat16* qr      = (__hip_bfloat16*)(ws + 0);
  __hip_bfloat16* kr      = (__hip_bfloat16*)(ws + 16777216);
  __hip_bfloat16* vt      = (__hip_bfloat16*)(ws + 33554432);
  __hip_bfloat16* obf     = (__hip_bfloat16*)(ws + 50331648);
  __hip_bfloat16* wo_bf   = (__hip_bfloat16*)(ws + 67108864);   // 32 MB
  float*          cos_t   = (float*)(ws + 100663296);
  float*          sin_t   = (float*)(ws + 100663296 + 524288);
  __hip_bfloat16* qkv_bf  = (__hip_bfloat16*)(ws + 117440512);  // 48 MB -> total 160 MB

  cvt_bf16_kernel<<<4096, 256, 0, stream>>>(hidden, hid_bf, 8388608L);
  cvt_bf16_kernel<<<8192, 256, 0, stream>>>(wqkv_w, wqkv_bf, 50331648L);
  gemm256_qkv_kernel<<<dim3(8, 48), 512, 0, stream>>>(hid_bf, wqkv_bf, wqkv_b, qkv_bf);
  // safe to overwrite wqkv region only after the QKV GEMM
  cvt_bf16_kernel<<<8192, 256, 0, stream>>>(wo_w, wo_bf, 16777216L);
  rope_table_kernel<<<2048, 64, 0, stream>>>(pos, cos_t, sin_t);
  rope_rearrange_kernel<<<dim3(32, 32), 256, 0, stream>>>(qkv_bf, cos_t, sin_t, qr, kr, vt);
  flash_attn_kernel<<<dim3(16, 32), 256, 0, stream>>>(qr, kr, vt, obf);
  gemm_bt_kernel<0><<<dim3(16, 32), 256, 0, stream>>>(obf, wo_bf, wo_b, out, 2048, 4096, 4096);
}